// Round 2
// baseline (190.129 us; speedup 1.0000x reference)
//
#include <hip/hip_runtime.h>

// AttentionGroupPool: B=8192 rows, T=4096, 64 ragged groups (sizes cycle
// 32/64/96/64; one cycle = 256 elems = 4 groups; 16 cycles per row).
//
// One WAVE per row, no LDS, no barriers. At float4-iteration k the wave's 64
// lanes cover exactly cycle k (elements [256k, 256k+256)). Group boundaries
// fall on aligned 8-lane blocks: lanes 0-7 | 8-23 | 24-47 | 48-63.
//  - xor-shuffle 1,2,4  -> every lane holds its aligned 8-lane block sum
//  - 3 bpermute gathers -> each lane j=l&3 has cycle-group-j's sum
//  - lane g = 4k+j keeps group g  -> after 16 iters, lane l holds group l
// Then a fully in-wave softmax over the 64 groups and a coalesced 256B write.

#define TPB 256

__global__ __launch_bounds__(TPB) void agp_kernel(
    const float* __restrict__ H,
    const float* __restrict__ score_w,
    const float* __restrict__ score_b,
    float* __restrict__ Z,
    float* __restrict__ A)
{
  const int lane = threadIdx.x & 63;
  const int wave = threadIdx.x >> 6;
  const int row  = blockIdx.x * 4 + wave;

  const float4* row4 = (const float4*)(H + (size_t)row * 4096);

  const int j   = lane & 3;   // group position within cycle
  const int myk = lane >> 2;  // which iteration owns this lane's group

  // gather sources (lane holding each needed 8-block sum = 8*block_index)
  // groups use blocks: j0:{0}  j1:{1,2}  j2:{3,4,5}  j3:{6,7}
  const int srcA = (j == 0) ? 0  : (j == 1) ? 8  : (j == 2) ? 24 : 48;
  const int srcB = (j == 1) ? 16 : (j == 2) ? 32 : 56;  // unused for j==0
  const int srcC = 40;                                   // only j==2

  float acc = 0.f;
#pragma unroll
  for (int k = 0; k < 16; ++k) {
    float4 v = row4[64 * k + lane];          // coalesced 1 KB per wave-iter
    float s = (v.x + v.y) + (v.z + v.w);
    s += __shfl_xor(s, 1);
    s += __shfl_xor(s, 2);
    s += __shfl_xor(s, 4);                   // aligned 8-lane block sum
    float t0 = __shfl(s, srcA);
    float t1 = __shfl(s, srcB);
    float t2 = __shfl(s, srcC);
    float g = t0;
    if (j >= 1) g += t1;
    if (j == 2) g += t2;
    if (k == myk) acc = g;                   // lane 4k+j owns group 4k+j
  }

  const float invsz = (j == 0) ? (1.f / 32.f)
                    : (j == 2) ? (1.f / 96.f)
                               : (1.f / 64.f);
  const float G     = acc * invsz;
  const float score = G * score_w[0] + score_b[0];

  // in-wave softmax over 64 groups
  float m = score;
#pragma unroll
  for (int mask = 32; mask >= 1; mask >>= 1)
    m = fmaxf(m, __shfl_xor(m, mask));

  const float e = __expf(score - m);
  float se = e;        // sum exp
  float sg = e * G;    // sum exp * G
#pragma unroll
  for (int mask = 32; mask >= 1; mask >>= 1) {
    se += __shfl_xor(se, mask);
    sg += __shfl_xor(sg, mask);
  }

  A[(size_t)row * 64 + lane] = e / se;       // 256 B coalesced per wave
  if (lane == 0) Z[row] = sg / se;
}

extern "C" void kernel_launch(void* const* d_in, const int* in_sizes, int n_in,
                              void* d_out, int out_size, void* d_ws, size_t ws_size,
                              hipStream_t stream) {
  const float* H  = (const float*)d_in[0];
  const float* sw = (const float*)d_in[1];
  const float* sb = (const float*)d_in[2];

  const int T = 4096;
  const int B = in_sizes[0] / T;   // 8192

  float* Z = (float*)d_out;        // [B]
  float* A = Z + B;                // [B, 64]

  agp_kernel<<<B / 4, TPB, 0, stream>>>(H, sw, sb, Z, A);
}